// Round 1
// baseline (1280.891 us; speedup 1.0000x reference)
//
#include <hip/hip_runtime.h>
#include <hip/hip_bf16.h>

#define T_TOK 4096
#define H_DIM 1024
#define E_EXP 64
#define TOPK  8
#define F_DIM 512
#define CAP   1024
#define A_TOT (T_TOK * TOPK)   // 32768

typedef _Float16 f16;
typedef _Float16 f16x2 __attribute__((ext_vector_type(2)));
typedef _Float16 f16x8 __attribute__((ext_vector_type(8)));
typedef float    f32x4 __attribute__((ext_vector_type(4)));

// ---------------------------------------------------------------------------
// K1: router — fp32 logits, top-8 (stable), renormalized weights.
// Block = 256 threads handles 16 tokens; thread (wave tg, lane e) does expert e
// for 4 tokens. w_gate [H,E] reads are lane-coalesced (256B/wave).
// ---------------------------------------------------------------------------
__global__ __launch_bounds__(256) void router_kernel(
    const float* __restrict__ x, const float* __restrict__ wg,
    float* __restrict__ logits_out, int* __restrict__ sel,
    float* __restrict__ wgtA)
{
    __shared__ float xs[16][128];
    __shared__ float ls[16][65];   // +1 pad: conflict-free top-k scans
    const int tid = threadIdx.x;
    const int e  = tid & 63;
    const int tg = tid >> 6;               // wave id 0..3 -> tokens tg*4..tg*4+3
    const int tb = blockIdx.x * 16;

    float acc[4] = {0.f, 0.f, 0.f, 0.f};
    for (int h0 = 0; h0 < H_DIM; h0 += 128) {
        {
            int r  = tid >> 4;             // 0..15
            int c0 = (tid & 15) * 8;
            const float4* src = (const float4*)(x + (size_t)(tb + r) * H_DIM + h0 + c0);
            float4 v0 = src[0], v1 = src[1];
            *(float4*)&xs[r][c0]     = v0;
            *(float4*)&xs[r][c0 + 4] = v1;
        }
        __syncthreads();
        for (int hh = 0; hh < 128; ++hh) {
            float w = wg[(size_t)(h0 + hh) * E_EXP + e];
            #pragma unroll
            for (int i = 0; i < 4; ++i)
                acc[i] = fmaf(xs[tg * 4 + i][hh], w, acc[i]);
        }
        __syncthreads();
    }
    #pragma unroll
    for (int i = 0; i < 4; ++i) {
        int tt = tg * 4 + i;
        logits_out[(size_t)(tb + tt) * E_EXP + e] = acc[i];
        ls[tt][e] = acc[i];
    }
    __syncthreads();
    if (tid < 16) {
        int tt = tid;
        float lv[8]; int li[8];
        for (int k = 0; k < 8; ++k) {
            float m = -1e30f; int mi = 0;
            for (int j = 0; j < 64; ++j) {
                float v = ls[tt][j];
                if (v > m) { m = v; mi = j; }   // strict > : lowest index wins ties (stable)
            }
            lv[k] = m; li[k] = mi;
            ls[tt][mi] = -1e30f;
        }
        // softmax denominator cancels under top-k renormalization
        float s = 0.f, wv[8];
        for (int k = 0; k < 8; ++k) { wv[k] = __expf(lv[k] - lv[0]); s += wv[k]; }
        float inv = 1.f / s;
        for (int k = 0; k < 8; ++k) {
            int a = (tb + tt) * TOPK + k;
            sel[a]  = li[k];
            wgtA[a] = wv[k] * inv;
        }
    }
}

// ---------------------------------------------------------------------------
// K2: per-expert stable token lists (order = flat assignment index, matching
// jnp.argsort(stable)). Capacity drop at pos >= CAP replicated.
// ---------------------------------------------------------------------------
__global__ __launch_bounds__(256) void build_lists_kernel(
    const int* __restrict__ sel, const float* __restrict__ wgtA,
    int* __restrict__ tok_list, float* __restrict__ wgt_list,
    int* __restrict__ counts)
{
    __shared__ int sc[256];
    const int e = blockIdx.x;
    const int tid = threadIdx.x;
    const int per = A_TOT / 256;   // 128 contiguous assignments per thread
    const int a0 = tid * per;
    int cnt = 0;
    for (int i = 0; i < per; ++i) cnt += (sel[a0 + i] == e) ? 1 : 0;
    sc[tid] = cnt;
    __syncthreads();
    for (int s = 1; s < 256; s <<= 1) {
        int v = (tid >= s) ? sc[tid - s] : 0;
        __syncthreads();
        sc[tid] += v;
        __syncthreads();
    }
    int total = sc[255];
    int pos = sc[tid] - cnt;       // exclusive prefix
    if (tid == 0) counts[e] = (total < CAP) ? total : CAP;
    for (int i = 0; i < per; ++i) {
        int a = a0 + i;
        if (sel[a] == e) {
            if (pos < CAP) {
                tok_list[e * CAP + pos] = a >> 3;   // token = a / K
                wgt_list[e * CAP + pos] = wgtA[a];
            }
            pos++;
        }
    }
}

// ---------------------------------------------------------------------------
// K3a: P[slot][f] = silu(x@w1) * (x@w3), fp16 MFMA 16x16x32.
// Block: expert z, 64-slot m-tile (x), 64-col f-tile (y). BK=64.
// W tiles transposed into LDS ([f][k], k-contiguous) during staging.
// ---------------------------------------------------------------------------
__global__ __launch_bounds__(256) void gemm1_kernel(
    const float* __restrict__ x, const float* __restrict__ w1,
    const float* __restrict__ w3, const int* __restrict__ tok_list,
    const int* __restrict__ counts, f16* __restrict__ P)
{
    const int e = blockIdx.z;
    const int cnt = counts[e];
    const int m0 = blockIdx.x * 64;
    if (m0 >= cnt) return;
    const int bf = blockIdx.y * 64;

    __shared__ f16 Xs[64][72];
    __shared__ f16 W1t[64][72];
    __shared__ f16 W3t[64][72];
    __shared__ int tok_s[64];

    const int tid = threadIdx.x;
    if (tid < 64) {
        int m = m0 + tid;
        tok_s[tid] = (m < cnt) ? tok_list[e * CAP + m] : tok_list[e * CAP];
    }

    const int ka = tid & 15, ff = tid >> 4;   // weight staging map
    const int kf = tid & 15, mr = tid >> 4;   // X staging map
    const int wv = tid >> 6, lane = tid & 63;
    const int jj = lane & 15, qq = lane >> 4;

    f32x4 accG[4], accU[4];
    #pragma unroll
    for (int i = 0; i < 4; ++i) {
        accG[i] = (f32x4){0.f, 0.f, 0.f, 0.f};
        accU[i] = (f32x4){0.f, 0.f, 0.f, 0.f};
    }

    const size_t wbase = (size_t)e * H_DIM * F_DIM + bf;

    for (int k0 = 0; k0 < H_DIM; k0 += 64) {
        __syncthreads();
        // stage X (gathered rows, fp32 -> fp16)
        #pragma unroll
        for (int s2 = 0; s2 < 4; ++s2) {
            int m = mr + 16 * s2;
            const float4 v = *(const float4*)(x + (size_t)tok_s[m] * H_DIM + k0 + 4 * kf);
            f16x2 p0; p0.x = (f16)v.x; p0.y = (f16)v.y;
            f16x2 p1; p1.x = (f16)v.z; p1.y = (f16)v.w;
            *(f16x2*)&Xs[m][4 * kf]     = p0;
            *(f16x2*)&Xs[m][4 * kf + 2] = p1;
        }
        // stage W1/W3 transposed: LDS [f][k]
        #pragma unroll
        for (int s2 = 0; s2 < 2; ++s2) {
            int kr = 2 * ka + 32 * s2;
            const float4 a0 = *(const float4*)(w1 + wbase + (size_t)(k0 + kr) * F_DIM + 4 * ff);
            const float4 a1 = *(const float4*)(w1 + wbase + (size_t)(k0 + kr + 1) * F_DIM + 4 * ff);
            const float4 b0 = *(const float4*)(w3 + wbase + (size_t)(k0 + kr) * F_DIM + 4 * ff);
            const float4 b1 = *(const float4*)(w3 + wbase + (size_t)(k0 + kr + 1) * F_DIM + 4 * ff);
            f16x2 t;
            t.x = (f16)a0.x; t.y = (f16)a1.x; *(f16x2*)&W1t[4 * ff + 0][kr] = t;
            t.x = (f16)a0.y; t.y = (f16)a1.y; *(f16x2*)&W1t[4 * ff + 1][kr] = t;
            t.x = (f16)a0.z; t.y = (f16)a1.z; *(f16x2*)&W1t[4 * ff + 2][kr] = t;
            t.x = (f16)a0.w; t.y = (f16)a1.w; *(f16x2*)&W1t[4 * ff + 3][kr] = t;
            t.x = (f16)b0.x; t.y = (f16)b1.x; *(f16x2*)&W3t[4 * ff + 0][kr] = t;
            t.x = (f16)b0.y; t.y = (f16)b1.y; *(f16x2*)&W3t[4 * ff + 1][kr] = t;
            t.x = (f16)b0.z; t.y = (f16)b1.z; *(f16x2*)&W3t[4 * ff + 2][kr] = t;
            t.x = (f16)b0.w; t.y = (f16)b1.w; *(f16x2*)&W3t[4 * ff + 3][kr] = t;
        }
        __syncthreads();
        #pragma unroll
        for (int ks = 0; ks < 2; ++ks) {
            f16x8 bG = *(const f16x8*)&W1t[wv * 16 + jj][ks * 32 + qq * 8];
            f16x8 bU = *(const f16x8*)&W3t[wv * 16 + jj][ks * 32 + qq * 8];
            #pragma unroll
            for (int mt = 0; mt < 4; ++mt) {
                f16x8 af = *(const f16x8*)&Xs[mt * 16 + jj][ks * 32 + qq * 8];
                accG[mt] = __builtin_amdgcn_mfma_f32_16x16x32_f16(af, bG, accG[mt], 0, 0, 0);
                accU[mt] = __builtin_amdgcn_mfma_f32_16x16x32_f16(af, bU, accU[mt], 0, 0, 0);
            }
        }
    }
    // epilogue: silu(g)*u -> fp16 P
    #pragma unroll
    for (int mt = 0; mt < 4; ++mt) {
        #pragma unroll
        for (int r = 0; r < 4; ++r) {
            int row = mt * 16 + qq * 4 + r;
            float g = accG[mt][r], u = accU[mt][r];
            float p = g / (1.f + __expf(-g)) * u;
            P[(size_t)(e * CAP + m0 + row) * F_DIM + bf + wv * 16 + jj] = (f16)p;
        }
    }
}

// ---------------------------------------------------------------------------
// K3b: Y = P @ w2, epilogue: out[token] += weight * Y row (fp32 atomics).
// ---------------------------------------------------------------------------
__global__ __launch_bounds__(256) void gemm2_kernel(
    const f16* __restrict__ P, const float* __restrict__ w2,
    const int* __restrict__ tok_list, const float* __restrict__ wgt_list,
    const int* __restrict__ counts, float* __restrict__ out)
{
    const int e = blockIdx.z;
    const int cnt = counts[e];
    const int m0 = blockIdx.x * 64;
    if (m0 >= cnt) return;
    const int h0 = blockIdx.y * 64;

    __shared__ f16 Ps[64][72];
    __shared__ f16 W2t[64][72];
    __shared__ int   tok_s[64];
    __shared__ float wgt_s[64];

    const int tid = threadIdx.x;
    if (tid < 64) {
        int m = m0 + tid;
        tok_s[tid] = (m < cnt) ? tok_list[e * CAP + m] : 0;
        wgt_s[tid] = (m < cnt) ? wgt_list[e * CAP + m] : 0.f;
    }

    const int ka = tid & 15, ff = tid >> 4;
    const int c8 = tid & 7,  pmr = tid >> 3;   // P staging: rows pmr, pmr+32
    const int wv = tid >> 6, lane = tid & 63;
    const int jj = lane & 15, qq = lane >> 4;

    f32x4 acc[4];
    #pragma unroll
    for (int i = 0; i < 4; ++i) acc[i] = (f32x4){0.f, 0.f, 0.f, 0.f};

    const size_t pbase  = (size_t)(e * CAP + m0) * F_DIM;
    const size_t w2base = (size_t)e * F_DIM * H_DIM + h0;

    for (int k0 = 0; k0 < F_DIM; k0 += 64) {
        __syncthreads();
        #pragma unroll
        for (int s2 = 0; s2 < 2; ++s2) {
            int m = pmr + 32 * s2;
            f16x8 v = *(const f16x8*)(P + pbase + (size_t)m * F_DIM + k0 + 8 * c8);
            *(f16x8*)&Ps[m][8 * c8] = v;
        }
        #pragma unroll
        for (int s2 = 0; s2 < 2; ++s2) {
            int kr = 2 * ka + 32 * s2;
            const float4 a0 = *(const float4*)(w2 + w2base + (size_t)(k0 + kr) * H_DIM + 4 * ff);
            const float4 a1 = *(const float4*)(w2 + w2base + (size_t)(k0 + kr + 1) * H_DIM + 4 * ff);
            f16x2 t;
            t.x = (f16)a0.x; t.y = (f16)a1.x; *(f16x2*)&W2t[4 * ff + 0][kr] = t;
            t.x = (f16)a0.y; t.y = (f16)a1.y; *(f16x2*)&W2t[4 * ff + 1][kr] = t;
            t.x = (f16)a0.z; t.y = (f16)a1.z; *(f16x2*)&W2t[4 * ff + 2][kr] = t;
            t.x = (f16)a0.w; t.y = (f16)a1.w; *(f16x2*)&W2t[4 * ff + 3][kr] = t;
        }
        __syncthreads();
        #pragma unroll
        for (int ks = 0; ks < 2; ++ks) {
            f16x8 bf_ = *(const f16x8*)&W2t[wv * 16 + jj][ks * 32 + qq * 8];
            #pragma unroll
            for (int mt = 0; mt < 4; ++mt) {
                f16x8 af = *(const f16x8*)&Ps[mt * 16 + jj][ks * 32 + qq * 8];
                acc[mt] = __builtin_amdgcn_mfma_f32_16x16x32_f16(af, bf_, acc[mt], 0, 0, 0);
            }
        }
    }
    #pragma unroll
    for (int mt = 0; mt < 4; ++mt) {
        #pragma unroll
        for (int r = 0; r < 4; ++r) {
            int row = mt * 16 + qq * 4 + r;
            if (m0 + row < cnt) {
                float y = acc[mt][r] * wgt_s[row];
                unsafeAtomicAdd(&out[(size_t)tok_s[row] * H_DIM + h0 + wv * 16 + jj], y);
            }
        }
    }
}

extern "C" void kernel_launch(void* const* d_in, const int* in_sizes, int n_in,
                              void* d_out, int out_size, void* d_ws, size_t ws_size,
                              hipStream_t stream) {
    const float* x  = (const float*)d_in[0];   // [B,S,H] = [T,H]
    const float* wg = (const float*)d_in[1];   // [H,E]
    const float* w1 = (const float*)d_in[2];   // [E,H,F]
    const float* w3 = (const float*)d_in[3];   // [E,H,F]
    const float* w2 = (const float*)d_in[4];   // [E,F,H]

    float* out    = (float*)d_out;                       // [T,H]
    float* logits = out + (size_t)T_TOK * H_DIM;         // [T,E]

    char* ws = (char*)d_ws;
    int*   sel      = (int*)  (ws);             // A ints      (128 KB)
    float* wgtA     = (float*)(ws + 131072);    // A floats    (128 KB)
    int*   tok_list = (int*)  (ws + 262144);    // E*CAP ints  (256 KB)
    float* wgt_list = (float*)(ws + 524288);    // E*CAP f32   (256 KB)
    int*   counts   = (int*)  (ws + 786432);    // E ints
    f16*   P        = (f16*)  (ws + 1048576);   // E*CAP*F fp16 (64 MB)

    hipMemsetAsync(out, 0, (size_t)T_TOK * H_DIM * sizeof(float), stream);
    router_kernel<<<T_TOK / 16, 256, 0, stream>>>(x, wg, logits, sel, wgtA);
    build_lists_kernel<<<E_EXP, 256, 0, stream>>>(sel, wgtA, tok_list, wgt_list, counts);
    gemm1_kernel<<<dim3(CAP / 64, F_DIM / 64, E_EXP), 256, 0, stream>>>(
        x, w1, w3, tok_list, counts, P);
    gemm2_kernel<<<dim3(CAP / 64, H_DIM / 64, E_EXP), 256, 0, stream>>>(
        P, w2, tok_list, wgt_list, counts, out);
}

// Round 2
// 742.808 us; speedup vs baseline: 1.7244x; 1.7244x over previous
//
#include <hip/hip_runtime.h>
#include <hip/hip_bf16.h>

#define T_TOK 4096
#define H_DIM 1024
#define E_EXP 64
#define TOPK  8
#define F_DIM 512
#define CAP   1024
#define A_TOT (T_TOK * TOPK)   // 32768

typedef _Float16 f16;
typedef _Float16 f16x2 __attribute__((ext_vector_type(2)));
typedef _Float16 f16x8 __attribute__((ext_vector_type(8)));
typedef float    f32x4 __attribute__((ext_vector_type(4)));

// ---------------------------------------------------------------------------
// K0: pack weights fp32 [E][Kd][Nd] -> fp16 B-fragment-packed:
// dst chunk (e, nt, kt) of 512 f16; lane l holds src[e][kt*32+(l>>4)*8+j][nt*16+(l&15)]
// so a wave's 1KB contiguous read IS the 16x16x32 MFMA B operand.
// ---------------------------------------------------------------------------
__global__ __launch_bounds__(256) void pack_w_kernel(
    const float* __restrict__ src, f16* __restrict__ dst, int Kd, int Nd)
{
    const int lane = threadIdx.x & 63;
    const int wv   = threadIdx.x >> 6;
    const int nt_cnt = Nd >> 4, kt_cnt = Kd >> 5;
    int chunk = blockIdx.x * 4 + wv;                 // [e][kt][nt] iteration order (coalesced reads)
    int nt = chunk % nt_cnt;
    int kt = (chunk / nt_cnt) % kt_cnt;
    int e  = chunk / (nt_cnt * kt_cnt);
    const float* s = src + ((size_t)e * Kd + kt * 32 + (lane >> 4) * 8) * Nd
                         + nt * 16 + (lane & 15);
    f16x8 v;
    #pragma unroll
    for (int j = 0; j < 8; ++j) v[j] = (f16)s[(size_t)j * Nd];
    // dst stored [e][nt][kt] (gemm reads kt-sequentially per fixed nt)
    size_t dchunk = ((size_t)e * nt_cnt + nt) * kt_cnt + kt;
    *(f16x8*)(dst + dchunk * 512 + lane * 8) = v;
}

// ---------------------------------------------------------------------------
// K1: router — fp32 logits, top-8 (stable), renormalized weights.
// Also emits xh = fp16 copy of x (staged tiles are already in registers).
// ---------------------------------------------------------------------------
__global__ __launch_bounds__(256) void router_kernel(
    const float* __restrict__ x, const float* __restrict__ wg,
    float* __restrict__ logits_out, int* __restrict__ sel,
    float* __restrict__ wgtA, f16* __restrict__ xh)
{
    __shared__ float xs[16][128];
    __shared__ float ls[16][65];
    const int tid = threadIdx.x;
    const int e  = tid & 63;
    const int tg = tid >> 6;
    const int tb = blockIdx.x * 16;

    float acc[4] = {0.f, 0.f, 0.f, 0.f};
    for (int h0 = 0; h0 < H_DIM; h0 += 128) {
        {
            int r  = tid >> 4;
            int c0 = (tid & 15) * 8;
            const float4* src = (const float4*)(x + (size_t)(tb + r) * H_DIM + h0 + c0);
            float4 v0 = src[0], v1 = src[1];
            *(float4*)&xs[r][c0]     = v0;
            *(float4*)&xs[r][c0 + 4] = v1;
            f16x8 hv;
            hv[0] = (f16)v0.x; hv[1] = (f16)v0.y; hv[2] = (f16)v0.z; hv[3] = (f16)v0.w;
            hv[4] = (f16)v1.x; hv[5] = (f16)v1.y; hv[6] = (f16)v1.z; hv[7] = (f16)v1.w;
            *(f16x8*)(xh + (size_t)(tb + r) * H_DIM + h0 + c0) = hv;
        }
        __syncthreads();
        for (int hh = 0; hh < 128; ++hh) {
            float w = wg[(size_t)(h0 + hh) * E_EXP + e];
            #pragma unroll
            for (int i = 0; i < 4; ++i)
                acc[i] = fmaf(xs[tg * 4 + i][hh], w, acc[i]);
        }
        __syncthreads();
    }
    #pragma unroll
    for (int i = 0; i < 4; ++i) {
        int tt = tg * 4 + i;
        logits_out[(size_t)(tb + tt) * E_EXP + e] = acc[i];
        ls[tt][e] = acc[i];
    }
    __syncthreads();
    if (tid < 16) {
        int tt = tid;
        float lv[8]; int li[8];
        for (int k = 0; k < 8; ++k) {
            float m = -1e30f; int mi = 0;
            for (int j = 0; j < 64; ++j) {
                float v = ls[tt][j];
                if (v > m) { m = v; mi = j; }   // strict > : lowest index wins (stable)
            }
            lv[k] = m; li[k] = mi;
            ls[tt][mi] = -1e30f;
        }
        float s = 0.f, wv[8];
        for (int k = 0; k < 8; ++k) { wv[k] = __expf(lv[k] - lv[0]); s += wv[k]; }
        float inv = 1.f / s;
        for (int k = 0; k < 8; ++k) {
            int a = (tb + tt) * TOPK + k;
            sel[a]  = li[k];
            wgtA[a] = wv[k] * inv;
        }
    }
}

// ---------------------------------------------------------------------------
// K2: per-expert stable token lists + capacity drop (matches argsort(stable)).
// ---------------------------------------------------------------------------
__global__ __launch_bounds__(256) void build_lists_kernel(
    const int* __restrict__ sel, const float* __restrict__ wgtA,
    int* __restrict__ tok_list, float* __restrict__ wgt_list,
    int* __restrict__ counts)
{
    __shared__ int sc[256];
    const int e = blockIdx.x;
    const int tid = threadIdx.x;
    const int per = A_TOT / 256;
    const int a0 = tid * per;
    int cnt = 0;
    for (int i = 0; i < per; ++i) cnt += (sel[a0 + i] == e) ? 1 : 0;
    sc[tid] = cnt;
    __syncthreads();
    for (int s = 1; s < 256; s <<= 1) {
        int v = (tid >= s) ? sc[tid - s] : 0;
        __syncthreads();
        sc[tid] += v;
        __syncthreads();
    }
    int total = sc[255];
    int pos = sc[tid] - cnt;
    if (tid == 0) counts[e] = (total < CAP) ? total : CAP;
    for (int i = 0; i < per; ++i) {
        int a = a0 + i;
        if (sel[a] == e) {
            if (pos < CAP) {
                tok_list[e * CAP + pos] = a >> 3;
                wgt_list[e * CAP + pos] = wgtA[a];
            }
            pos++;
        }
    }
}

#define MFMA16(a, b, c) __builtin_amdgcn_mfma_f32_16x16x32_f16(a, b, c, 0, 0, 0)

// ---------------------------------------------------------------------------
// K3a: P = silu(x@w1)*(x@w3). B-frags straight from packed global (prefetched
// one K-iter ahead); only gathered A tile goes through LDS. Grid swizzled so
// the 16 m-tiles of one (e,f) group land on one XCD (id%8 round-robin).
// ---------------------------------------------------------------------------
__global__ __launch_bounds__(256) void gemm1_kernel(
    const f16* __restrict__ xh, const f16* __restrict__ w1p,
    const f16* __restrict__ w3p, const int* __restrict__ tok_list,
    const int* __restrict__ counts, f16* __restrict__ P)
{
    const int id = blockIdx.x;
    const int rest = id >> 3;
    const int g  = (id & 7) + ((rest >> 4) << 3);   // 0..511 = (e, f-tile)
    const int m0 = (rest & 15) * 64;
    const int bf = (g & 7) * 64;
    const int e  = g >> 3;
    const int cnt = counts[e];
    if (m0 >= cnt) return;

    __shared__ f16 Xs[64][72];
    __shared__ int tok_s[64];

    const int tid = threadIdx.x;
    const int lane = tid & 63, wv = tid >> 6;
    const int jj = lane & 15, qq = lane >> 4;

    if (tid < 64) {
        int m = m0 + tid;
        tok_s[tid] = (m < cnt) ? tok_list[e * CAP + m] : tok_list[e * CAP];
    }
    __syncthreads();

    const int sr = tid >> 3, sc = (tid & 7) * 8;

    const f16* w1b = w1p + ((size_t)e * 32 + (bf >> 4) + wv) * 32 * 512 + lane * 8;
    const f16* w3b = w3p + ((size_t)e * 32 + (bf >> 4) + wv) * 32 * 512 + lane * 8;

    f32x4 accG[4], accU[4];
    #pragma unroll
    for (int i = 0; i < 4; ++i) {
        accG[i] = (f32x4){0.f, 0.f, 0.f, 0.f};
        accU[i] = (f32x4){0.f, 0.f, 0.f, 0.f};
    }

    f16x8 pG0 = *(const f16x8*)(w1b);
    f16x8 pG1 = *(const f16x8*)(w1b + 512);
    f16x8 pU0 = *(const f16x8*)(w3b);
    f16x8 pU1 = *(const f16x8*)(w3b + 512);

    for (int k0 = 0; k0 < H_DIM; k0 += 64) {
        f16x8 x0 = *(const f16x8*)(xh + (size_t)tok_s[sr]      * H_DIM + k0 + sc);
        f16x8 x1 = *(const f16x8*)(xh + (size_t)tok_s[sr + 32] * H_DIM + k0 + sc);
        __syncthreads();
        *(f16x8*)&Xs[sr][sc]      = x0;
        *(f16x8*)&Xs[sr + 32][sc] = x1;
        __syncthreads();
        f16x8 cG0 = pG0, cG1 = pG1, cU0 = pU0, cU1 = pU1;
        if (k0 + 64 < H_DIM) {
            size_t kg = (size_t)((k0 >> 5) + 2) * 512;
            pG0 = *(const f16x8*)(w1b + kg);
            pG1 = *(const f16x8*)(w1b + kg + 512);
            pU0 = *(const f16x8*)(w3b + kg);
            pU1 = *(const f16x8*)(w3b + kg + 512);
        }
        #pragma unroll
        for (int mt = 0; mt < 4; ++mt) {
            f16x8 a0 = *(const f16x8*)&Xs[mt * 16 + jj][qq * 8];
            f16x8 a1 = *(const f16x8*)&Xs[mt * 16 + jj][32 + qq * 8];
            accG[mt] = MFMA16(a0, cG0, accG[mt]);
            accU[mt] = MFMA16(a0, cU0, accU[mt]);
            accG[mt] = MFMA16(a1, cG1, accG[mt]);
            accU[mt] = MFMA16(a1, cU1, accU[mt]);
        }
    }
    #pragma unroll
    for (int mt = 0; mt < 4; ++mt) {
        #pragma unroll
        for (int r = 0; r < 4; ++r) {
            int row = mt * 16 + qq * 4 + r;
            float gg = accG[mt][r], u = accU[mt][r];
            float p = gg / (1.f + __expf(-gg)) * u;
            P[(size_t)(e * CAP + m0 + row) * F_DIM + bf + wv * 16 + jj] = (f16)p;
        }
    }
}

// ---------------------------------------------------------------------------
// K3b: Y = P @ w2, weighted atomic scatter to out.
// ---------------------------------------------------------------------------
__global__ __launch_bounds__(256) void gemm2_kernel(
    const f16* __restrict__ P, const f16* __restrict__ w2p,
    const int* __restrict__ tok_list, const float* __restrict__ wgt_list,
    const int* __restrict__ counts, float* __restrict__ out)
{
    const int id = blockIdx.x;
    const int rest = id >> 3;
    const int g  = (id & 7) + ((rest >> 4) << 3);   // 0..1023 = (e, h-tile)
    const int m0 = (rest & 15) * 64;
    const int h0 = (g & 15) * 64;
    const int e  = g >> 4;
    const int cnt = counts[e];
    if (m0 >= cnt) return;

    __shared__ f16   Ps[64][72];
    __shared__ int   tok_s[64];
    __shared__ float wgt_s[64];

    const int tid = threadIdx.x;
    const int lane = tid & 63, wv = tid >> 6;
    const int jj = lane & 15, qq = lane >> 4;

    if (tid < 64) {
        int m = m0 + tid;
        tok_s[tid] = (m < cnt) ? tok_list[e * CAP + m] : 0;
        wgt_s[tid] = (m < cnt) ? wgt_list[e * CAP + m] : 0.f;
    }

    const int sr = tid >> 3, sc = (tid & 7) * 8;
    const size_t pbase = (size_t)(e * CAP + m0) * F_DIM;

    const f16* w2b = w2p + ((size_t)e * 64 + (h0 >> 4) + wv) * 16 * 512 + lane * 8;

    f32x4 acc[4];
    #pragma unroll
    for (int i = 0; i < 4; ++i) acc[i] = (f32x4){0.f, 0.f, 0.f, 0.f};

    f16x8 p0 = *(const f16x8*)(w2b);
    f16x8 p1 = *(const f16x8*)(w2b + 512);

    for (int k0 = 0; k0 < F_DIM; k0 += 64) {
        f16x8 x0 = *(const f16x8*)(P + pbase + (size_t)sr        * F_DIM + k0 + sc);
        f16x8 x1 = *(const f16x8*)(P + pbase + (size_t)(sr + 32) * F_DIM + k0 + sc);
        __syncthreads();
        *(f16x8*)&Ps[sr][sc]      = x0;
        *(f16x8*)&Ps[sr + 32][sc] = x1;
        __syncthreads();
        f16x8 c0 = p0, c1 = p1;
        if (k0 + 64 < F_DIM) {
            size_t kg = (size_t)((k0 >> 5) + 2) * 512;
            p0 = *(const f16x8*)(w2b + kg);
            p1 = *(const f16x8*)(w2b + kg + 512);
        }
        #pragma unroll
        for (int mt = 0; mt < 4; ++mt) {
            f16x8 a0 = *(const f16x8*)&Ps[mt * 16 + jj][qq * 8];
            f16x8 a1 = *(const f16x8*)&Ps[mt * 16 + jj][32 + qq * 8];
            acc[mt] = MFMA16(a0, c0, acc[mt]);
            acc[mt] = MFMA16(a1, c1, acc[mt]);
        }
    }
    #pragma unroll
    for (int mt = 0; mt < 4; ++mt) {
        #pragma unroll
        for (int r = 0; r < 4; ++r) {
            int row = mt * 16 + qq * 4 + r;
            if (m0 + row < cnt) {
                float y = acc[mt][r] * wgt_s[row];
                unsafeAtomicAdd(&out[(size_t)tok_s[row] * H_DIM + h0 + wv * 16 + jj], y);
            }
        }
    }
}

extern "C" void kernel_launch(void* const* d_in, const int* in_sizes, int n_in,
                              void* d_out, int out_size, void* d_ws, size_t ws_size,
                              hipStream_t stream) {
    const float* x  = (const float*)d_in[0];   // [T,H]
    const float* wg = (const float*)d_in[1];   // [H,E]
    const float* w1 = (const float*)d_in[2];   // [E,H,F]
    const float* w3 = (const float*)d_in[3];   // [E,H,F]
    const float* w2 = (const float*)d_in[4];   // [E,F,H]

    float* out    = (float*)d_out;
    float* logits = out + (size_t)T_TOK * H_DIM;

    char* ws = (char*)d_ws;
    int*   sel      = (int*)  (ws);
    float* wgtA     = (float*)(ws + (128 << 10));
    int*   tok_list = (int*)  (ws + (256 << 10));
    float* wgt_list = (float*)(ws + (512 << 10));
    int*   counts   = (int*)  (ws + (768 << 10));
    f16*   xh       = (f16*)  (ws + (size_t)(1 << 20));     // 8 MB
    f16*   P        = (f16*)  (ws + (size_t)(9 << 20));     // 64 MB
    f16*   w1p      = (f16*)  (ws + (size_t)(73 << 20));    // 64 MB
    f16*   w3p      = (f16*)  (ws + (size_t)(137 << 20));   // 64 MB
    f16*   w2p      = (f16*)  (ws + (size_t)(201 << 20));   // 64 MB (end 265 MB)

    hipMemsetAsync(out, 0, (size_t)T_TOK * H_DIM * sizeof(float), stream);
    pack_w_kernel<<<16384, 256, 0, stream>>>(w1, w1p, H_DIM, F_DIM);
    pack_w_kernel<<<16384, 256, 0, stream>>>(w3, w3p, H_DIM, F_DIM);
    pack_w_kernel<<<16384, 256, 0, stream>>>(w2, w2p, F_DIM, H_DIM);
    router_kernel<<<T_TOK / 16, 256, 0, stream>>>(x, wg, logits, sel, wgtA, xh);
    build_lists_kernel<<<E_EXP, 256, 0, stream>>>(sel, wgtA, tok_list, wgt_list, counts);
    gemm1_kernel<<<16 * 8 * E_EXP, 256, 0, stream>>>(xh, w1p, w3p, tok_list, counts, P);
    gemm2_kernel<<<16 * 16 * E_EXP, 256, 0, stream>>>(P, w2p, tok_list, wgt_list, counts, out);
}

// Round 3
// 711.297 us; speedup vs baseline: 1.8008x; 1.0443x over previous
//
#include <hip/hip_runtime.h>
#include <hip/hip_bf16.h>

#define T_TOK 4096
#define H_DIM 1024
#define E_EXP 64
#define TOPK  8
#define F_DIM 512
#define CAP   1024
#define A_TOT (T_TOK * TOPK)   // 32768

typedef _Float16 f16;
typedef _Float16 f16x2 __attribute__((ext_vector_type(2)));
typedef _Float16 f16x4 __attribute__((ext_vector_type(4)));
typedef _Float16 f16x8 __attribute__((ext_vector_type(8)));
typedef float    f32x4 __attribute__((ext_vector_type(4)));

// ---------------------------------------------------------------------------
// K0: pack fp32 [E][Kd][Nd] -> fp16 B-fragment chunks [e][nt][kt] of 512 f16.
// Chunk (e,nt,kt): lane l, slot j holds src[e][kt*32+(l>>4)*8+j][nt*16+(l&15)]
// so one wave's contiguous 1KB read IS a 16x16x32 MFMA B operand (2 k-halves).
// Block: 32k x 128n tile; float4 coalesced reads -> LDS transpose -> b128 store.
// ---------------------------------------------------------------------------
__global__ __launch_bounds__(256) void pack_w_kernel(
    const float* __restrict__ src, f16* __restrict__ dst, int Kd, int Nd)
{
    __shared__ f16 tile[32][132];   // stride 132: 8-row groups land bank-offset 16 -> 2-way (free)
    const int tid = threadIdx.x;
    const int nb = Nd >> 7;
    const int kb = Kd >> 5;
    const int b = blockIdx.x;
    const int n0  = (b % nb) * 128;
    const int kt0 = (b / nb) % kb;
    const int e   = b / (nb * kb);

    const float* s = src + ((size_t)e * Kd + kt0 * 32) * Nd + n0;
    #pragma unroll
    for (int rep = 0; rep < 4; ++rep) {
        int idx = rep * 256 + tid;
        int r = idx >> 5, c = (idx & 31) * 4;
        float4 v = *(const float4*)(s + (size_t)r * Nd + c);
        f16x4 h; h[0] = (f16)v.x; h[1] = (f16)v.y; h[2] = (f16)v.z; h[3] = (f16)v.w;
        *(f16x4*)&tile[r][c] = h;
    }
    __syncthreads();
    const int lane = tid & 63, wv = tid >> 6;
    #pragma unroll
    for (int ci = 0; ci < 2; ++ci) {
        int c = wv + ci * 4;                       // n-sub-tile of 16 cols
        f16x8 v;
        #pragma unroll
        for (int j = 0; j < 8; ++j)
            v[j] = tile[(lane >> 4) * 8 + j][c * 16 + (lane & 15)];
        int nt = (n0 >> 4) + c;
        size_t chunk = ((size_t)e * (Nd >> 4) + nt) * kb + kt0;
        *(f16x8*)(dst + chunk * 512 + lane * 8) = v;
    }
}

// ---------------------------------------------------------------------------
// K1: router — fp32 logits, top-8 (stable), renormalized weights; emits fp16 x.
// ---------------------------------------------------------------------------
__global__ __launch_bounds__(256) void router_kernel(
    const float* __restrict__ x, const float* __restrict__ wg,
    float* __restrict__ logits_out, int* __restrict__ sel,
    float* __restrict__ wgtA, f16* __restrict__ xh)
{
    __shared__ float xs[16][128];
    __shared__ float ls[16][65];
    const int tid = threadIdx.x;
    const int e  = tid & 63;
    const int tg = tid >> 6;
    const int tb = blockIdx.x * 16;

    float acc[4] = {0.f, 0.f, 0.f, 0.f};
    for (int h0 = 0; h0 < H_DIM; h0 += 128) {
        {
            int r  = tid >> 4;
            int c0 = (tid & 15) * 8;
            const float4* src = (const float4*)(x + (size_t)(tb + r) * H_DIM + h0 + c0);
            float4 v0 = src[0], v1 = src[1];
            *(float4*)&xs[r][c0]     = v0;
            *(float4*)&xs[r][c0 + 4] = v1;
            f16x8 hv;
            hv[0] = (f16)v0.x; hv[1] = (f16)v0.y; hv[2] = (f16)v0.z; hv[3] = (f16)v0.w;
            hv[4] = (f16)v1.x; hv[5] = (f16)v1.y; hv[6] = (f16)v1.z; hv[7] = (f16)v1.w;
            *(f16x8*)(xh + (size_t)(tb + r) * H_DIM + h0 + c0) = hv;
        }
        __syncthreads();
        for (int hh = 0; hh < 128; ++hh) {
            float w = wg[(size_t)(h0 + hh) * E_EXP + e];
            #pragma unroll
            for (int i = 0; i < 4; ++i)
                acc[i] = fmaf(xs[tg * 4 + i][hh], w, acc[i]);
        }
        __syncthreads();
    }
    #pragma unroll
    for (int i = 0; i < 4; ++i) {
        int tt = tg * 4 + i;
        logits_out[(size_t)(tb + tt) * E_EXP + e] = acc[i];
        ls[tt][e] = acc[i];
    }
    __syncthreads();
    if (tid < 16) {
        int tt = tid;
        float lv[8]; int li[8];
        for (int k = 0; k < 8; ++k) {
            float m = -1e30f; int mi = 0;
            for (int j = 0; j < 64; ++j) {
                float v = ls[tt][j];
                if (v > m) { m = v; mi = j; }   // strict > : lowest index wins (stable)
            }
            lv[k] = m; li[k] = mi;
            ls[tt][mi] = -1e30f;
        }
        float s = 0.f, wv[8];
        for (int k = 0; k < 8; ++k) { wv[k] = __expf(lv[k] - lv[0]); s += wv[k]; }
        float inv = 1.f / s;
        for (int k = 0; k < 8; ++k) {
            int a = (tb + tt) * TOPK + k;
            sel[a]  = li[k];
            wgtA[a] = wv[k] * inv;
        }
    }
}

// ---------------------------------------------------------------------------
// K2: per-expert stable token lists + capacity drop (matches argsort(stable)).
// ---------------------------------------------------------------------------
__global__ __launch_bounds__(256) void build_lists_kernel(
    const int* __restrict__ sel, const float* __restrict__ wgtA,
    int* __restrict__ tok_list, float* __restrict__ wgt_list,
    int* __restrict__ counts)
{
    __shared__ int sc[256];
    const int e = blockIdx.x;
    const int tid = threadIdx.x;
    const int per = A_TOT / 256;
    const int a0 = tid * per;
    int cnt = 0;
    for (int i = 0; i < per; ++i) cnt += (sel[a0 + i] == e) ? 1 : 0;
    sc[tid] = cnt;
    __syncthreads();
    for (int s = 1; s < 256; s <<= 1) {
        int v = (tid >= s) ? sc[tid - s] : 0;
        __syncthreads();
        sc[tid] += v;
        __syncthreads();
    }
    int total = sc[255];
    int pos = sc[tid] - cnt;
    if (tid == 0) counts[e] = (total < CAP) ? total : CAP;
    for (int i = 0; i < per; ++i) {
        int a = a0 + i;
        if (sel[a] == e) {
            if (pos < CAP) {
                tok_list[e * CAP + pos] = a >> 3;
                wgt_list[e * CAP + pos] = wgtA[a];
            }
            pos++;
        }
    }
}

#define MFMA16(a, b, c) __builtin_amdgcn_mfma_f32_16x16x32_f16(a, b, c, 0, 0, 0)

// ---------------------------------------------------------------------------
// K3a: P = silu(x@w1)*(x@w3). Software-pipelined: double-buffered LDS A-tile,
// one barrier/iter, A+W for iter k+1 issued before iter k's MFMAs.
// Grid: id = (e&7) + 8*((e>>3)*128 + mt*8 + ft) -> expert pinned to one XCD.
// ---------------------------------------------------------------------------
__global__ __launch_bounds__(256) void gemm1_kernel(
    const f16* __restrict__ xh, const f16* __restrict__ w1p,
    const f16* __restrict__ w3p, const int* __restrict__ tok_list,
    const int* __restrict__ counts, f16* __restrict__ P)
{
    const int id = blockIdx.x;
    const int x7 = id & 7, r = id >> 3;
    const int ft = r & 7, mt = (r >> 3) & 15, eh = r >> 7;
    const int e = x7 + 8 * eh;
    const int cnt = counts[e];
    const int m0 = mt * 64;
    if (m0 >= cnt) return;
    const int bf = ft * 64;

    __shared__ f16 Xs[2][64][72];
    __shared__ int tok_s[64];

    const int tid = threadIdx.x;
    const int lane = tid & 63, wv = tid >> 6;
    const int jj = lane & 15, qq = lane >> 4;
    const int sr = tid >> 3, sc = (tid & 7) * 8;

    if (tid < 64) {
        int m = m0 + tid;
        tok_s[tid] = (m < cnt) ? tok_list[e * CAP + m] : tok_list[e * CAP];
    }
    __syncthreads();
    const size_t rowA = (size_t)tok_s[sr] * H_DIM + sc;
    const size_t rowB = (size_t)tok_s[sr + 32] * H_DIM + sc;

    const f16* w1b = w1p + (((size_t)e * 32 + ft * 4 + wv) * 32) * 512 + lane * 8;
    const f16* w3b = w3p + (((size_t)e * 32 + ft * 4 + wv) * 32) * 512 + lane * 8;

    f32x4 accG[4], accU[4];
    #pragma unroll
    for (int i = 0; i < 4; ++i) {
        accG[i] = (f32x4){0.f, 0.f, 0.f, 0.f};
        accU[i] = (f32x4){0.f, 0.f, 0.f, 0.f};
    }

    // prologue: stage k-block 0 + first weight frags
    {
        f16x8 a = *(const f16x8*)(xh + rowA);
        f16x8 b = *(const f16x8*)(xh + rowB);
        *(f16x8*)&Xs[0][sr][sc]      = a;
        *(f16x8*)&Xs[0][sr + 32][sc] = b;
    }
    f16x8 cG0 = *(const f16x8*)(w1b);
    f16x8 cG1 = *(const f16x8*)(w1b + 512);
    f16x8 cU0 = *(const f16x8*)(w3b);
    f16x8 cU1 = *(const f16x8*)(w3b + 512);

    #pragma unroll
    for (int it = 0; it < 16; ++it) {
        const int k0 = it * 64;
        __syncthreads();                       // Xs[it&1] visible; prior readers of Xs[(it+1)&1] done
        f16x8 xn0, xn1, nG0, nG1, nU0, nU1;
        if (it < 15) {                         // issue next-iter loads before MFMAs
            xn0 = *(const f16x8*)(xh + rowA + k0 + 64);
            xn1 = *(const f16x8*)(xh + rowB + k0 + 64);
            size_t kg = (size_t)(2 * it + 2) * 512;
            nG0 = *(const f16x8*)(w1b + kg);
            nG1 = *(const f16x8*)(w1b + kg + 512);
            nU0 = *(const f16x8*)(w3b + kg);
            nU1 = *(const f16x8*)(w3b + kg + 512);
        }
        const int buf = it & 1;
        #pragma unroll
        for (int m2 = 0; m2 < 4; ++m2) {
            f16x8 a0 = *(const f16x8*)&Xs[buf][m2 * 16 + jj][qq * 8];
            f16x8 a1 = *(const f16x8*)&Xs[buf][m2 * 16 + jj][32 + qq * 8];
            accG[m2] = MFMA16(a0, cG0, accG[m2]);
            accU[m2] = MFMA16(a0, cU0, accU[m2]);
            accG[m2] = MFMA16(a1, cG1, accG[m2]);
            accU[m2] = MFMA16(a1, cU1, accU[m2]);
        }
        if (it < 15) {
            *(f16x8*)&Xs[buf ^ 1][sr][sc]      = xn0;
            *(f16x8*)&Xs[buf ^ 1][sr + 32][sc] = xn1;
            cG0 = nG0; cG1 = nG1; cU0 = nU0; cU1 = nU1;
        }
    }
    #pragma unroll
    for (int m2 = 0; m2 < 4; ++m2) {
        #pragma unroll
        for (int rr = 0; rr < 4; ++rr) {
            int row = m2 * 16 + qq * 4 + rr;
            float gg = accG[m2][rr], u = accU[m2][rr];
            float p = gg / (1.f + __expf(-gg)) * u;
            P[(size_t)(e * CAP + m0 + row) * F_DIM + bf + wv * 16 + jj] = (f16)p;
        }
    }
}

// ---------------------------------------------------------------------------
// K3b: Y = P @ w2, weighted atomic scatter. N=128/block (2 B-cols per wave:
// each LDS A-read feeds 2 MFMAs). Same pipeline + XCD pinning as gemm1.
// ---------------------------------------------------------------------------
__global__ __launch_bounds__(256) void gemm2_kernel(
    const f16* __restrict__ P, const f16* __restrict__ w2p,
    const int* __restrict__ tok_list, const float* __restrict__ wgt_list,
    const int* __restrict__ counts, float* __restrict__ out)
{
    const int id = blockIdx.x;
    const int x7 = id & 7, r = id >> 3;
    const int ht = r & 7, mt = (r >> 3) & 15, eh = r >> 7;
    const int e = x7 + 8 * eh;
    const int cnt = counts[e];
    const int m0 = mt * 64;
    if (m0 >= cnt) return;
    const int h0 = ht * 128;

    __shared__ f16   Ps[2][64][72];
    __shared__ int   tok_s[64];
    __shared__ float wgt_s[64];

    const int tid = threadIdx.x;
    const int lane = tid & 63, wv = tid >> 6;
    const int jj = lane & 15, qq = lane >> 4;
    const int sr = tid >> 3, sc = (tid & 7) * 8;

    if (tid < 64) {
        int m = m0 + tid;
        tok_s[tid] = (m < cnt) ? tok_list[e * CAP + m] : 0;
        wgt_s[tid] = (m < cnt) ? wgt_list[e * CAP + m] : 0.f;
    }

    const size_t pbase = (size_t)(e * CAP + m0) * F_DIM;
    const f16* wA = w2p + (((size_t)e * 64 + ht * 8 + wv) * 16) * 512 + lane * 8;
    const f16* wB = w2p + (((size_t)e * 64 + ht * 8 + wv + 4) * 16) * 512 + lane * 8;

    f32x4 accA[4], accB[4];
    #pragma unroll
    for (int i = 0; i < 4; ++i) {
        accA[i] = (f32x4){0.f, 0.f, 0.f, 0.f};
        accB[i] = (f32x4){0.f, 0.f, 0.f, 0.f};
    }

    {
        f16x8 a = *(const f16x8*)(P + pbase + (size_t)sr * F_DIM + sc);
        f16x8 b = *(const f16x8*)(P + pbase + (size_t)(sr + 32) * F_DIM + sc);
        *(f16x8*)&Ps[0][sr][sc]      = a;
        *(f16x8*)&Ps[0][sr + 32][sc] = b;
    }
    f16x8 cA0 = *(const f16x8*)(wA);
    f16x8 cA1 = *(const f16x8*)(wA + 512);
    f16x8 cB0 = *(const f16x8*)(wB);
    f16x8 cB1 = *(const f16x8*)(wB + 512);

    #pragma unroll
    for (int it = 0; it < 8; ++it) {
        const int k0 = it * 64;
        __syncthreads();
        f16x8 pn0, pn1, nA0, nA1, nB0, nB1;
        if (it < 7) {
            pn0 = *(const f16x8*)(P + pbase + (size_t)sr * F_DIM + k0 + 64 + sc);
            pn1 = *(const f16x8*)(P + pbase + (size_t)(sr + 32) * F_DIM + k0 + 64 + sc);
            size_t kg = (size_t)(2 * it + 2) * 512;
            nA0 = *(const f16x8*)(wA + kg);
            nA1 = *(const f16x8*)(wA + kg + 512);
            nB0 = *(const f16x8*)(wB + kg);
            nB1 = *(const f16x8*)(wB + kg + 512);
        }
        const int buf = it & 1;
        #pragma unroll
        for (int m2 = 0; m2 < 4; ++m2) {
            f16x8 a0 = *(const f16x8*)&Ps[buf][m2 * 16 + jj][qq * 8];
            f16x8 a1 = *(const f16x8*)&Ps[buf][m2 * 16 + jj][32 + qq * 8];
            accA[m2] = MFMA16(a0, cA0, accA[m2]);
            accB[m2] = MFMA16(a0, cB0, accB[m2]);
            accA[m2] = MFMA16(a1, cA1, accA[m2]);
            accB[m2] = MFMA16(a1, cB1, accB[m2]);
        }
        if (it < 7) {
            *(f16x8*)&Ps[buf ^ 1][sr][sc]      = pn0;
            *(f16x8*)&Ps[buf ^ 1][sr + 32][sc] = pn1;
            cA0 = nA0; cA1 = nA1; cB0 = nB0; cB1 = nB1;
        }
    }
    #pragma unroll
    for (int m2 = 0; m2 < 4; ++m2) {
        #pragma unroll
        for (int rr = 0; rr < 4; ++rr) {
            int row = m2 * 16 + qq * 4 + rr;
            if (m0 + row < cnt) {
                float w = wgt_s[row];
                float* obase = &out[(size_t)tok_s[row] * H_DIM + h0 + wv * 16 + jj];
                unsafeAtomicAdd(obase,      accA[m2][rr] * w);
                unsafeAtomicAdd(obase + 64, accB[m2][rr] * w);
            }
        }
    }
}

extern "C" void kernel_launch(void* const* d_in, const int* in_sizes, int n_in,
                              void* d_out, int out_size, void* d_ws, size_t ws_size,
                              hipStream_t stream) {
    const float* x  = (const float*)d_in[0];   // [T,H]
    const float* wg = (const float*)d_in[1];   // [H,E]
    const float* w1 = (const float*)d_in[2];   // [E,H,F]
    const float* w3 = (const float*)d_in[3];   // [E,H,F]
    const float* w2 = (const float*)d_in[4];   // [E,F,H]

    float* out    = (float*)d_out;
    float* logits = out + (size_t)T_TOK * H_DIM;

    char* ws = (char*)d_ws;
    int*   sel      = (int*)  (ws);
    float* wgtA     = (float*)(ws + (128 << 10));
    int*   tok_list = (int*)  (ws + (256 << 10));
    float* wgt_list = (float*)(ws + (512 << 10));
    int*   counts   = (int*)  (ws + (768 << 10));
    f16*   xh       = (f16*)  (ws + (size_t)(1 << 20));     // 8 MB
    f16*   P        = (f16*)  (ws + (size_t)(9 << 20));     // 64 MB
    f16*   w1p      = (f16*)  (ws + (size_t)(73 << 20));    // 64 MB
    f16*   w3p      = (f16*)  (ws + (size_t)(137 << 20));   // 64 MB
    f16*   w2p      = (f16*)  (ws + (size_t)(201 << 20));   // 64 MB (end 265 MB)

    hipMemsetAsync(out, 0, (size_t)T_TOK * H_DIM * sizeof(float), stream);
    pack_w_kernel<<<8192, 256, 0, stream>>>(w1, w1p, H_DIM, F_DIM);   // 64*32*4
    pack_w_kernel<<<8192, 256, 0, stream>>>(w3, w3p, H_DIM, F_DIM);
    pack_w_kernel<<<8192, 256, 0, stream>>>(w2, w2p, F_DIM, H_DIM);   // 64*16*8
    router_kernel<<<T_TOK / 16, 256, 0, stream>>>(x, wg, logits, sel, wgtA, xh);
    build_lists_kernel<<<E_EXP, 256, 0, stream>>>(sel, wgtA, tok_list, wgt_list, counts);
    gemm1_kernel<<<8192, 256, 0, stream>>>(xh, w1p, w3p, tok_list, counts, P);
    gemm2_kernel<<<8192, 256, 0, stream>>>(P, w2p, tok_list, wgt_list, counts, out);
}